// Round 1
// baseline (10119.238 us; speedup 1.0000x reference)
//
#include <hip/hip_runtime.h>

// VQ-VAE VectorQuantizer: z (32,256,32,32) f32, emb (1024,256) f32
// -> d_out: [32768 floats: argmin indices in (B,H,W) order] + [1 float: loss]
//
// Correctness strategy: bit-replicate numpy's f32 computation.
//   distances = (sumz + sume) - 2.0*(z @ e.T), all f32, argmin first-index.
//   sumz/sume: numpy pairwise summation (two 128-blocks, 8-way unrolled).
//   dot: f64 accumulation rounded to f32 (within ~ulp of BLAS f32 dot; final
//   rounding at ~3e-5 grid absorbs the difference).

#define NE      1024
#define DIM     256
#define BHW     32768
#define CSTRIDE 1024     // H*W
#define BSTRIDE 262144   // C*H*W
#define RPB     4        // z-rows per block
#define NTH     256

// numpy pairwise_sum of squares, n=128 block (8<=n<=128 path):
// r[0..7]=a[0..7]; r[k]+=a[i+k]; combine ((r0+r1)+(r2+r3))+((r4+r5)+(r6+r7))
__device__ __forceinline__ float np_pw128_sq(const float* p) {
    float r[8];
#pragma unroll
    for (int k = 0; k < 8; ++k) r[k] = __fmul_rn(p[k], p[k]);
    for (int i = 8; i < 128; i += 8) {
#pragma unroll
        for (int k = 0; k < 8; ++k)
            r[k] = __fadd_rn(r[k], __fmul_rn(p[i + k], p[i + k]));
    }
    return __fadd_rn(__fadd_rn(__fadd_rn(r[0], r[1]), __fadd_rn(r[2], r[3])),
                     __fadd_rn(__fadd_rn(r[4], r[5]), __fadd_rn(r[6], r[7])));
}
// n=256: split into two 128 halves (numpy: n2 = n/2 rounded to mult of 8)
__device__ __forceinline__ float np_pw256_sq(const float* p) {
    return __fadd_rn(np_pw128_sq(p), np_pw128_sq(p + 128));
}

__global__ void vq_init(double* acc) { *acc = 0.0; }

__global__ __launch_bounds__(NTH) void vq_sume(const float* __restrict__ emb,
                                               float* __restrict__ sume) {
    int j = blockIdx.x * NTH + threadIdx.x;
    if (j < NE) sume[j] = np_pw256_sq(emb + (size_t)j * DIM);
}

__global__ __launch_bounds__(NTH) void vq_main(const float* __restrict__ z,
                                               const float* __restrict__ emb,
                                               const float* __restrict__ sume,
                                               float* __restrict__ out,
                                               double* __restrict__ loss_acc) {
    __shared__ float  zs[RPB][DIM];
    __shared__ float  sd[NTH];
    __shared__ int    sj[NTH];
    __shared__ int    winners[RPB];
    __shared__ double sdd[NTH];

    const int t    = threadIdx.x;
    const int row0 = blockIdx.x * RPB;

    // stage RPB z-rows into LDS. row n=(b,h,w): elem c at b*BSTRIDE + hw + c*CSTRIDE
#pragma unroll
    for (int r = 0; r < RPB; ++r) {
        int n = row0 + r;
        int b = n >> 10, hw = n & 1023;
        zs[r][t] = z[(size_t)b * BSTRIDE + hw + (size_t)t * CSTRIDE];
    }
    __syncthreads();

    // per-row sum(z^2), numpy pairwise (redundant per thread, cheap)
    float t1[RPB];
#pragma unroll
    for (int r = 0; r < RPB; ++r) t1[r] = np_pw256_sq(zs[r]);

    // f64 dot accumulation: thread t owns codes j = t + jj*256
    double acc[RPB][4];
#pragma unroll
    for (int r = 0; r < RPB; ++r)
#pragma unroll
        for (int jj = 0; jj < 4; ++jj) acc[r][jj] = 0.0;

    for (int c = 0; c < DIM; ++c) {
        float zc[RPB];
#pragma unroll
        for (int r = 0; r < RPB; ++r) zc[r] = zs[r][c];
#pragma unroll
        for (int jj = 0; jj < 4; ++jj) {
            float ec = emb[(size_t)(t + jj * 256) * DIM + c];
            double ecd = (double)ec;
#pragma unroll
            for (int r = 0; r < RPB; ++r)
                acc[r][jj] = fma((double)zc[r], ecd, acc[r][jj]);
        }
    }

    // distances + local argmin (ascending j, strict < => first-occurrence)
    float bestd[RPB];
    int   bestj[RPB];
#pragma unroll
    for (int r = 0; r < RPB; ++r) {
        float bd = 3.4e38f;
        int   bj = 0;
#pragma unroll
        for (int jj = 0; jj < 4; ++jj) {
            int   j    = t + jj * 256;
            float dotf = (float)acc[r][jj];
            float d    = __fsub_rn(__fadd_rn(t1[r], sume[j]),
                                   __fmul_rn(2.0f, dotf));
            if (d < bd) { bd = d; bj = j; }
        }
        bestd[r] = bd;
        bestj[r] = bj;
    }

    // block argmin per row, smaller-index tie-break
    for (int r = 0; r < RPB; ++r) {
        sd[t] = bestd[r];
        sj[t] = bestj[r];
        __syncthreads();
        for (int s = NTH / 2; s > 0; s >>= 1) {
            if (t < s) {
                float od = sd[t + s];
                int   oj = sj[t + s];
                if (od < sd[t] || (od == sd[t] && oj < sj[t])) {
                    sd[t] = od;
                    sj[t] = oj;
                }
            }
            __syncthreads();
        }
        if (t == 0) {
            winners[r]    = sj[0];
            out[row0 + r] = (float)sj[0];
        }
        __syncthreads();
    }

    // loss partial: sum over this block's rows of (e[j*] - z)^2, f32 elementwise
    double lsum = 0.0;
#pragma unroll
    for (int r = 0; r < RPB; ++r) {
        int   j    = winners[r];
        float diff = __fsub_rn(emb[(size_t)j * DIM + t], zs[r][t]);
        float sq   = __fmul_rn(diff, diff);
        lsum += (double)sq;
    }
    sdd[t] = lsum;
    __syncthreads();
    for (int s = NTH / 2; s > 0; s >>= 1) {
        if (t < s) sdd[t] += sdd[t + s];
        __syncthreads();
    }
    if (t == 0) atomicAdd(loss_acc, sdd[0]);
}

__global__ void vq_final(const double* __restrict__ acc,
                         float* __restrict__ out) {
    double m  = *acc / 8388608.0;
    float  mf = (float)m;
    out[BHW]  = __fadd_rn(mf, __fmul_rn(0.25f, mf));
}

extern "C" void kernel_launch(void* const* d_in, const int* in_sizes, int n_in,
                              void* d_out, int out_size, void* d_ws, size_t ws_size,
                              hipStream_t stream) {
    const float* z   = (const float*)d_in[0];
    const float* emb = (const float*)d_in[1];
    float*  out      = (float*)d_out;
    float*  sume     = (float*)d_ws;
    double* loss_acc = (double*)((char*)d_ws + 4096);

    vq_init<<<1, 1, 0, stream>>>(loss_acc);
    vq_sume<<<NE / NTH, NTH, 0, stream>>>(emb, sume);
    vq_main<<<BHW / RPB, NTH, 0, stream>>>(z, emb, sume, out, loss_acc);
    vq_final<<<1, 1, 0, stream>>>(loss_acc, out);
}

// Round 2
// 547.994 us; speedup vs baseline: 18.4660x; 18.4660x over previous
//
#include <hip/hip_runtime.h>

// VQ-VAE VectorQuantizer: z (32,256,32,32) f32, emb (1024,256) f32
// -> d_out: [32768 floats: argmin indices in (B,H,W) order] + [1 float: loss]
//
// Numerics (bit-replicates numpy, validated round 1 with absmax 0):
//   d = fl(fl(sumz + sume_j) - fl(2 * fl64->32(dot)))  all f32 ops explicit
//   sumz/sume via numpy pairwise summation (8-bucket, two 128-halves)
//   dot accumulated in f64 (order-independent at the 3e-5 output grid)
//   argmin: first-occurrence tie-break via packed (f32bits<<32 | j) min-key
//
// R2: register-blocked f64 distance-GEMM. 128x128 block tile, 8x8/thread,
// f64 LDS staging with 10-double group stride (2-way bank alias = free).

#define NE   1024
#define DIM  256
#define BHW  32768
#define CST  1024     // H*W
#define BST  262144   // C*H*W
#define NTH  256
#define MT   128      // rows per block
#define NT   128      // codes per tile
#define KT   16       // k chunk
#define RT   8        // rows per thread
#define CTY  8        // codes per thread
#define ZSTR 160      // doubles per k-row: 16 groups * (8 data + 2 pad)
#define NCHUNK (DIM / KT)  // 16
#define NCT    (NE / NT)   // 8

// ---- numpy pairwise sum-of-squares helpers (must stay bit-identical) ----
__device__ __forceinline__ float np_pw128_sq_contig(const float* p) {
    float r[8];
#pragma unroll
    for (int k = 0; k < 8; ++k) r[k] = __fmul_rn(p[k], p[k]);
    for (int i = 8; i < 128; i += 8) {
#pragma unroll
        for (int k = 0; k < 8; ++k)
            r[k] = __fadd_rn(r[k], __fmul_rn(p[i + k], p[i + k]));
    }
    return __fadd_rn(__fadd_rn(__fadd_rn(r[0], r[1]), __fadd_rn(r[2], r[3])),
                     __fadd_rn(__fadd_rn(r[4], r[5]), __fadd_rn(r[6], r[7])));
}

__global__ void vq_init(double* acc) { *acc = 0.0; }

__global__ __launch_bounds__(NTH) void vq_sume(const float* __restrict__ emb,
                                               float* __restrict__ sume) {
    int j = blockIdx.x * NTH + threadIdx.x;
    if (j < NE) {
        const float* p = emb + (size_t)j * DIM;
        sume[j] = __fadd_rn(np_pw128_sq_contig(p), np_pw128_sq_contig(p + 128));
    }
}

// per-row sum(z^2), numpy pairwise over the strided (B,C,H,W) layout.
// one thread per row; reads coalesced across rows for each fixed c.
__global__ __launch_bounds__(NTH) void vq_t1(const float* __restrict__ z,
                                             float* __restrict__ t1) {
    int n  = blockIdx.x * NTH + threadIdx.x;
    int b  = n >> 10, hw = n & 1023;
    const float* p = z + (size_t)b * BST + hw;
    float r[8];
#pragma unroll
    for (int k = 0; k < 8; ++k) { float v = p[(size_t)k * CST]; r[k] = __fmul_rn(v, v); }
    for (int c = 8; c < 128; ++c) {
        float v = p[(size_t)c * CST];
        r[c & 7] = __fadd_rn(r[c & 7], __fmul_rn(v, v));
    }
    float h1 = __fadd_rn(__fadd_rn(__fadd_rn(r[0], r[1]), __fadd_rn(r[2], r[3])),
                         __fadd_rn(__fadd_rn(r[4], r[5]), __fadd_rn(r[6], r[7])));
#pragma unroll
    for (int k = 0; k < 8; ++k) { float v = p[(size_t)(128 + k) * CST]; r[k] = __fmul_rn(v, v); }
    for (int c = 136; c < 256; ++c) {
        float v = p[(size_t)c * CST];
        r[c & 7] = __fadd_rn(r[c & 7], __fmul_rn(v, v));
    }
    float h2 = __fadd_rn(__fadd_rn(__fadd_rn(r[0], r[1]), __fadd_rn(r[2], r[3])),
                         __fadd_rn(__fadd_rn(r[4], r[5]), __fadd_rn(r[6], r[7])));
    t1[n] = __fadd_rn(h1, h2);
}

__global__ __launch_bounds__(NTH) void vq_main(const float* __restrict__ z,
                                               const float* __restrict__ emb,
                                               const float* __restrict__ sume,
                                               const float* __restrict__ t1g,
                                               float* __restrict__ out,
                                               double* __restrict__ loss_acc) {
    __shared__ double zs[KT * ZSTR];   // 20 KB
    __shared__ double es[KT * ZSTR];   // 20 KB
    __shared__ unsigned long long red[MT][16];  // 16 KB
    __shared__ int    winners[MT];
    __shared__ double sdd[NTH];

    const int tid  = threadIdx.x;
    const int rg   = tid & 15;        // row group  (8 rows)
    const int cg   = tid >> 4;        // code group (8 codes)
    const int row0 = blockIdx.x * MT;
    const int b    = row0 >> 10;
    const int hw0  = row0 & 1023;

    // staging roles
    const int sm  = tid & 127;        // z-stage row in tile
    const int skh = tid >> 7;         // z-stage k parity
    const int sn  = tid >> 1;         // e-stage code in tile
    const int skq = tid & 1;          // e-stage k half

    const float* zstg = z + (size_t)b * BST + hw0 + sm;   // + c*CST
    const int    zi   = (sm >> 3) * 10 + (sm & 7);
    const int    ei   = (sn >> 3) * 10 + (sn & 7);

    float t1v[RT];
#pragma unroll
    for (int i = 0; i < RT; ++i) t1v[i] = t1g[row0 + rg * RT + i];

    unsigned long long bestk[RT];
#pragma unroll
    for (int i = 0; i < RT; ++i) bestk[i] = ~0ull;

    for (int ct = 0; ct < NCT; ++ct) {
        double acc[RT][CTY];
#pragma unroll
        for (int i = 0; i < RT; ++i)
#pragma unroll
            for (int j = 0; j < CTY; ++j) acc[i][j] = 0.0;

        float smv[CTY];
#pragma unroll
        for (int j = 0; j < CTY; ++j) smv[j] = sume[ct * NT + cg * CTY + j];

        const float* estg = emb + (size_t)(ct * NT + sn) * DIM + skq * 8;

        for (int kt = 0; kt < NCHUNK; ++kt) {
            __syncthreads();
            // stage z: 8 elems/thread, coalesced across sm for each fixed c
            {
                const float* zp = zstg + (size_t)(kt * KT + skh) * CST;
#pragma unroll
                for (int kk = 0; kk < 8; ++kk) {
                    float v = zp[(size_t)(kk * 2) * CST];
                    zs[(kk * 2 + skh) * ZSTR + zi] = (double)v;
                }
            }
            // stage e: 8 contiguous k per thread (two float4 loads)
            {
                const float4* ep = (const float4*)(estg + kt * KT);
                float4 e0 = ep[0], e1 = ep[1];
                es[(skq * 8 + 0) * ZSTR + ei] = (double)e0.x;
                es[(skq * 8 + 1) * ZSTR + ei] = (double)e0.y;
                es[(skq * 8 + 2) * ZSTR + ei] = (double)e0.z;
                es[(skq * 8 + 3) * ZSTR + ei] = (double)e0.w;
                es[(skq * 8 + 4) * ZSTR + ei] = (double)e1.x;
                es[(skq * 8 + 5) * ZSTR + ei] = (double)e1.y;
                es[(skq * 8 + 6) * ZSTR + ei] = (double)e1.z;
                es[(skq * 8 + 7) * ZSTR + ei] = (double)e1.w;
            }
            __syncthreads();

#pragma unroll 2
            for (int k = 0; k < KT; ++k) {
                const double* zf = &zs[k * ZSTR + rg * 10];
                const double* ef = &es[k * ZSTR + cg * 10];
                double zr[RT], er[CTY];
#pragma unroll
                for (int i = 0; i < RT; ++i) zr[i] = zf[i];
#pragma unroll
                for (int j = 0; j < CTY; ++j) er[j] = ef[j];
#pragma unroll
                for (int i = 0; i < RT; ++i)
#pragma unroll
                    for (int j = 0; j < CTY; ++j)
                        acc[i][j] = fma(zr[i], er[j], acc[i][j]);
            }
        }

        // distances + running argmin (packed key keeps first-occurrence ties)
#pragma unroll
        for (int i = 0; i < RT; ++i)
#pragma unroll
            for (int j = 0; j < CTY; ++j) {
                float dotf = (float)acc[i][j];
                float d = __fsub_rn(__fadd_rn(t1v[i], smv[j]),
                                    __fmul_rn(2.0f, dotf));
                unsigned long long key =
                    ((unsigned long long)__float_as_uint(d) << 32) |
                    (unsigned)(ct * NT + cg * CTY + j);
                if (key < bestk[i]) bestk[i] = key;
            }
    }

    // block argmin across the 16 code-groups
#pragma unroll
    for (int i = 0; i < RT; ++i) red[rg * RT + i][cg] = bestk[i];
    __syncthreads();
    if (tid < MT) {
        unsigned long long k = red[tid][0];
#pragma unroll
        for (int c = 1; c < 16; ++c) { unsigned long long v = red[tid][c]; if (v < k) k = v; }
        int j = (int)(k & 0xffffffffu);
        winners[tid]   = j;
        out[row0 + tid] = (float)j;
    }
    __syncthreads();

    // loss partial: rows of this block, 2 threads per row
    {
        const int lm = tid & 127, lh = tid >> 7;
        int wj = winners[lm];
        const float* zr = z + (size_t)b * BST + hw0 + lm;
        const float* er = emb + (size_t)wj * DIM;
        double ls = 0.0;
        for (int c = lh * 128; c < lh * 128 + 128; ++c) {
            float diff = __fsub_rn(er[c], zr[(size_t)c * CST]);
            ls += (double)__fmul_rn(diff, diff);
        }
        sdd[tid] = ls;
    }
    __syncthreads();
    for (int s = NTH / 2; s > 0; s >>= 1) {
        if (tid < s) sdd[tid] += sdd[tid + s];
        __syncthreads();
    }
    if (tid == 0) atomicAdd(loss_acc, sdd[0]);
}

__global__ void vq_final(const double* __restrict__ acc,
                         float* __restrict__ out) {
    double m  = *acc / 8388608.0;
    float  mf = (float)m;
    out[BHW]  = __fadd_rn(mf, __fmul_rn(0.25f, mf));
}

extern "C" void kernel_launch(void* const* d_in, const int* in_sizes, int n_in,
                              void* d_out, int out_size, void* d_ws, size_t ws_size,
                              hipStream_t stream) {
    const float* z   = (const float*)d_in[0];
    const float* emb = (const float*)d_in[1];
    float*  out      = (float*)d_out;
    float*  sume     = (float*)d_ws;                       // 4 KB
    double* loss_acc = (double*)((char*)d_ws + 4096);      // 8 B
    float*  t1       = (float*)((char*)d_ws + 4104);       // 128 KB

    vq_init<<<1, 1, 0, stream>>>(loss_acc);
    vq_sume<<<NE / NTH, NTH, 0, stream>>>(emb, sume);
    vq_t1<<<BHW / NTH, NTH, 0, stream>>>(z, t1);
    vq_main<<<BHW / MT, NTH, 0, stream>>>(z, emb, sume, t1, out, loss_acc);
    vq_final<<<1, 1, 0, stream>>>(loss_acc, out);
}